// Round 4
// baseline (790.422 us; speedup 1.0000x reference)
//
#include <hip/hip_runtime.h>
#include <math.h>
#include <stdint.h>

#define D   512
#define K2  1024      // [hi || lo] fp16 split along K
#define HW  49
#define BM  128
#define BN  128
#define BK  32        // f16 elems per K-step (one 16x16x32 MFMA)
#define NSWEEP 4      // N-subtiles swept per block (amortizes atomics, A reuse)

typedef __attribute__((ext_vector_type(8))) _Float16 f16x8;  // 8 f16 (4 VGPRs)
typedef __attribute__((ext_vector_type(4))) float f32x4;
typedef __attribute__((address_space(3))) uint32_t lds_t;
typedef const __attribute__((address_space(1))) uint32_t glb_t;

// ---- GAP + fp16 hi/lo split: one thread per (b,c) row of x[2048,512,7,7] ----
// hi+lo captures ~22 mantissa bits -> reconstruction is fp32-exact for practical purposes.
__global__ void gap_split_kernel(const float* __restrict__ x,
                                 _Float16* __restrict__ emb2, int rows) {
    int r = blockIdx.x * blockDim.x + threadIdx.x;
    if (r >= rows) return;
    const float* p = x + (size_t)r * HW;
    float s = 0.f;
#pragma unroll
    for (int j = 0; j < HW; ++j) s += p[j];
    s *= (1.f / 49.f);
    _Float16 hi = (_Float16)s;
    _Float16 lo = (_Float16)(s - (float)hi);
    int m = r >> 9, c = r & 511;
    emb2[(size_t)m * K2 + c]       = hi;
    emb2[(size_t)m * K2 + 512 + c] = lo;
}

// ---- db fp32 -> fp16 hi/lo split, zero-padded to N2 rows ----
__global__ void split_db_kernel(const float* __restrict__ db,
                                _Float16* __restrict__ db2, int N, int N2) {
    int idx = blockIdx.x * blockDim.x + threadIdx.x;
    int n = idx >> 9, c = idx & 511;
    if (n >= N2) return;
    float v = (n < N) ? db[(size_t)n * D + c] : 0.f;
    _Float16 hi = (_Float16)v;
    _Float16 lo = (_Float16)(v - (float)hi);
    db2[(size_t)n * K2 + c]       = hi;
    db2[(size_t)n * K2 + 512 + c] = lo;
}

// ---- squared norm of RECONSTRUCTED (hi+lo) row -> consistent with MFMA dot ----
__global__ void sqnorm2_kernel(const _Float16* __restrict__ mat2, float* __restrict__ out) {
    int row = blockIdx.x;
    const _Float16* p = mat2 + (size_t)row * K2;
    float s = 0.f;
    for (int j = threadIdx.x; j < D; j += 64) {
        float v = (float)p[j] + (float)p[512 + j];
        s = fmaf(v, v, s);
    }
#pragma unroll
    for (int m = 32; m; m >>= 1) s += __shfl_xor(s, m, 64);
    if (threadIdx.x == 0) out[row] = s;
}

__global__ void init_keys_kernel(unsigned long long* __restrict__ keys, int M) {
    int b = blockIdx.x * blockDim.x + threadIdx.x;
    if (b < M) keys[b] = ~0ull;
}

// ---- fused f16-split MFMA GEMM + min/argmin ----
// grid (gx, M/128), 256 thr = 4 waves in 2x2; wave tile 64x64 = 4x4 frags of 16x16.
// m97 structure: linear LDS [128][32] f16, global_load_lds width=16, 2 barriers/K-step.
__global__ __launch_bounds__(256) void dist_kernel(
        const _Float16* __restrict__ A2, const _Float16* __restrict__ B2,
        const float* __restrict__ a2, const float* __restrict__ b2,
        unsigned long long* __restrict__ keys, int M, int N)
{
    __shared__ _Float16 As[BM * BK];   // 8 KB
    __shared__ _Float16 Bs[BN * BK];   // 8 KB
    const int tid  = threadIdx.x;
    const int lane = tid & 63;
    const int w    = tid >> 6;          // wave 0..3
    const int wr   = w >> 1, wc = w & 1;
    const int l15  = lane & 15;
    const int lg   = lane >> 4;         // 0..3
    const int mBase = blockIdx.y * BM;

    float a2r[4][4];                    // a2 for the 16 C-rows this lane produces
#pragma unroll
    for (int mF = 0; mF < 4; ++mF)
#pragma unroll
        for (int r = 0; r < 4; ++r)
            a2r[mF][r] = a2[mBase + wr * 64 + mF * 16 + lg * 4 + r];

    unsigned long long key[4][4];
#pragma unroll
    for (int mF = 0; mF < 4; ++mF)
#pragma unroll
        for (int r = 0; r < 4; ++r) key[mF][r] = ~0ull;

    const int o0 = w * 1024 + lane * 16;     // this lane's byte slot in a 4 KB stage chunk

    for (int s = 0; s < NSWEEP; ++s) {
        const int nBase = (blockIdx.x * NSWEEP + s) * BN;
        if (nBase >= N) break;               // uniform per block

        f32x4 acc[4][4];
#pragma unroll
        for (int mF = 0; mF < 4; ++mF)
#pragma unroll
            for (int nF = 0; nF < 4; ++nF) acc[mF][nF] = (f32x4){0.f, 0.f, 0.f, 0.f};

        for (int k0 = 0; k0 < K2; k0 += BK) {
            __syncthreads();   // previous tile's LDS reads done
#pragma unroll
            for (int q = 0; q < 2; ++q) {
                const int o   = o0 + q * 4096;     // byte offset in 8 KB tile
                const int row = o >> 6;            // tile row (64 B per row)
                const int cb  = o & 63;            // byte within row
                const char* ga = (const char*)A2 + ((size_t)(mBase + row) * K2 + k0) * 2 + cb;
                const char* gb = (const char*)B2 + ((size_t)(nBase + row) * K2 + k0) * 2 + cb;
                const int ldsoff = q * 4096 + w * 1024;   // wave-uniform dest base
                __builtin_amdgcn_global_load_lds((glb_t*)ga, (lds_t*)((char*)As + ldsoff), 16, 0, 0);
                __builtin_amdgcn_global_load_lds((glb_t*)gb, (lds_t*)((char*)Bs + ldsoff), 16, 0, 0);
            }
            __syncthreads();   // compiler drains vmcnt before barrier -> tiles ready

            f16x8 af[4], bfr[4];
#pragma unroll
            for (int mF = 0; mF < 4; ++mF)
                af[mF] = *(const f16x8*)(As + (wr * 64 + mF * 16 + l15) * BK + lg * 8);
#pragma unroll
            for (int nF = 0; nF < 4; ++nF)
                bfr[nF] = *(const f16x8*)(Bs + (wc * 64 + nF * 16 + l15) * BK + lg * 8);
#pragma unroll
            for (int mF = 0; mF < 4; ++mF)
#pragma unroll
                for (int nF = 0; nF < 4; ++nF)
                    acc[mF][nF] = __builtin_amdgcn_mfma_f32_16x16x32_f16(
                        af[mF], bfr[nF], acc[mF][nF], 0, 0, 0);
        }

        // epilogue: d2 = a2 - 2ab + b2, pack (d2_bits<<32)|idx, running per-lane min
#pragma unroll
        for (int nF = 0; nF < 4; ++nF) {
            const int g = nBase + wc * 64 + nF * 16 + l15;
            if (g < N) {
                const float b2c = b2[g];
#pragma unroll
                for (int mF = 0; mF < 4; ++mF)
#pragma unroll
                    for (int r = 0; r < 4; ++r) {
                        float d2 = fmaxf(fmaf(-2.f, acc[mF][nF][r], a2r[mF][r] + b2c), 0.f);
                        unsigned long long kk =
                            ((unsigned long long)__float_as_uint(d2) << 32) | (unsigned)g;
                        key[mF][r] = key[mF][r] < kk ? key[mF][r] : kk;
                    }
            }
        }
    }

    // reduce across the 16 lanes (same lg group) holding different cols of each row
#pragma unroll
    for (int mF = 0; mF < 4; ++mF)
#pragma unroll
        for (int r = 0; r < 4; ++r) {
            unsigned long long k = key[mF][r];
#pragma unroll
            for (int m = 1; m < 16; m <<= 1) {
                unsigned long long o = __shfl_xor(k, m, 16);
                k = k < o ? k : o;
            }
            if (l15 == 0)
                atomicMin(&keys[mBase + wr * 64 + mF * 16 + lg * 4 + r], k);
        }
}

__global__ void finalize_kernel(const unsigned long long* __restrict__ keys,
                                float* __restrict__ out_dist, float* __restrict__ out_idx, int M) {
    int b = blockIdx.x * blockDim.x + threadIdx.x;
    if (b >= M) return;
    unsigned long long k = keys[b];
    float d2 = __uint_as_float((unsigned)(k >> 32));
    out_dist[b] = sqrtf(fmaxf(d2, 0.f));
    out_idx[b]  = (float)(unsigned)(k & 0xffffffffu);  // idx as float VALUE (<2^24 exact)
}

extern "C" void kernel_launch(void* const* d_in, const int* in_sizes, int n_in,
                              void* d_out, int out_size, void* d_ws, size_t ws_size,
                              hipStream_t stream) {
    const float* x  = (const float*)d_in[0];
    const float* db = (const float*)d_in[1];
    float* out = (float*)d_out;

    const int M  = in_sizes[0] / (D * HW);              // 2048
    const int N  = in_sizes[1] / D;                     // 50000
    const int nTiles = (N + BN - 1) / BN;               // 391
    const int gx = (nTiles + NSWEEP - 1) / NSWEEP;      // 98
    const int N2 = gx * NSWEEP * BN;                    // 50176 (staging-safe padding)

    char* ws = (char*)d_ws;
    _Float16* emb2 = (_Float16*)ws;                     // M  x K2 (4 MB)
    _Float16* db2  = emb2 + (size_t)M * K2;             // N2 x K2 (~103 MB)
    float* a2 = (float*)(db2 + (size_t)N2 * K2);
    float* b2 = a2 + M;
    unsigned long long* keys =
        (unsigned long long*)(((uintptr_t)(b2 + N2) + 7) & ~(uintptr_t)7);

    const int rows = M * D;
    gap_split_kernel<<<(rows + 255) / 256, 256, 0, stream>>>(x, emb2, rows);
    split_db_kernel<<<((size_t)N2 * D + 255) / 256, 256, 0, stream>>>(db, db2, N, N2);
    sqnorm2_kernel<<<M, 64, 0, stream>>>(emb2, a2);
    sqnorm2_kernel<<<N, 64, 0, stream>>>(db2, b2);
    init_keys_kernel<<<(M + 255) / 256, 256, 0, stream>>>(keys, M);

    dim3 grid(gx, M / BM);
    dist_kernel<<<grid, 256, 0, stream>>>(emb2, db2, a2, b2, keys, M, N);

    finalize_kernel<<<(M + 255) / 256, 256, 0, stream>>>(keys, out, out + M, M);
}

// Round 6
// 642.498 us; speedup vs baseline: 1.2302x; 1.2302x over previous
//
#include <hip/hip_runtime.h>
#include <math.h>
#include <stdint.h>

#define D      512
#define K2T    1056      // [hi(512) | lo(512) | b2h,b2l,1,1 | zeros] padded to 33*32
#define HW     49
#define BM     128
#define BN     128
#define BK     32
#define NSWEEP 4
#define KSTEPS 33        // K2T / BK
#define TTOT   (NSWEEP * KSTEPS)

typedef __attribute__((ext_vector_type(8))) _Float16 f16x8;
typedef __attribute__((ext_vector_type(4))) float f32x4;
typedef __attribute__((address_space(3))) uint32_t lds_t;
typedef const __attribute__((address_space(1))) uint32_t glb_t;

// ---- GAP + fp16 hi/lo split: one thread per (b,c) row of x ----
__global__ void gap_split_kernel(const float* __restrict__ x,
                                 _Float16* __restrict__ emb2, int rows) {
    int r = blockIdx.x * blockDim.x + threadIdx.x;
    if (r >= rows) return;
    const float* p = x + (size_t)r * HW;
    float s = 0.f;
#pragma unroll
    for (int j = 0; j < HW; ++j) s += p[j];
    s *= (1.f / 49.f);
    _Float16 hi = (_Float16)s;
    _Float16 lo = (_Float16)(s - (float)hi);
    int m = r >> 9, c = r & 511;
    emb2[(size_t)m * K2T + c]       = hi;
    emb2[(size_t)m * K2T + 512 + c] = lo;
}

// ---- per-row a2 + A-tail [1,1,a2h,a2l,0...]: one wave per emb row ----
__global__ void finishA_kernel(_Float16* __restrict__ emb2, int M) {
    int row = blockIdx.x * 4 + (threadIdx.x >> 6);
    if (row >= M) return;
    int lane = threadIdx.x & 63;
    _Float16* p = emb2 + (size_t)row * K2T;
    f16x8 h = *(const f16x8*)(p + lane * 8);
    f16x8 l = *(const f16x8*)(p + 512 + lane * 8);
    float s = 0.f;
#pragma unroll
    for (int i = 0; i < 8; ++i) { float v = (float)h[i] + (float)l[i]; s = fmaf(v, v, s); }
#pragma unroll
    for (int m2 = 32; m2; m2 >>= 1) s += __shfl_xor(s, m2, 64);
    if (lane == 0) {
        _Float16 a2h = (_Float16)s;
        _Float16 a2l = (_Float16)(s - (float)a2h);
        _Float16 one = (_Float16)1.f, z0 = (_Float16)0.f;
        f16x8 t0 = {one, one, a2h, a2l, z0, z0, z0, z0};
        f16x8 z  = {z0, z0, z0, z0, z0, z0, z0, z0};
        *(f16x8*)(p + 1024) = t0;
        *(f16x8*)(p + 1032) = z;
        *(f16x8*)(p + 1040) = z;
        *(f16x8*)(p + 1048) = z;
    }
}

// ---- db -> [-2b split | b2h,b2l,1,1 | 0] fused with sqnorm: one wave per row ----
__global__ void split_db_kernel(const float* __restrict__ db,
                                _Float16* __restrict__ db2, int N, int N2) {
    int row = blockIdx.x * 4 + (threadIdx.x >> 6);
    if (row >= N2) return;
    int lane = threadIdx.x & 63;
    _Float16* q = db2 + (size_t)row * K2T;
    _Float16 z0 = (_Float16)0.f;
    f16x8 z = {z0, z0, z0, z0, z0, z0, z0, z0};
    if (row < N) {
        const float* p = db + (size_t)row * D + lane * 8;
        float4 v0 = *(const float4*)p;
        float4 v1 = *(const float4*)(p + 4);
        float vv[8] = {v0.x, v0.y, v0.z, v0.w, v1.x, v1.y, v1.z, v1.w};
        f16x8 h, l;
        float s = 0.f;
#pragma unroll
        for (int i = 0; i < 8; ++i) {
            float v = vv[i];
            s = fmaf(v, v, s);
            float wv = -2.f * v;                 // fold the -2 into B
            _Float16 hh = (_Float16)wv;
            h[i] = hh;
            l[i] = (_Float16)(wv - (float)hh);
        }
        *(f16x8*)(q + lane * 8)       = h;
        *(f16x8*)(q + 512 + lane * 8) = l;
#pragma unroll
        for (int m2 = 32; m2; m2 >>= 1) s += __shfl_xor(s, m2, 64);
        if (lane == 0) {
            _Float16 b2h = (_Float16)s;
            _Float16 b2l = (_Float16)(s - (float)b2h);
            _Float16 one = (_Float16)1.f;
            f16x8 t0 = {b2h, b2l, one, one, z0, z0, z0, z0};
            *(f16x8*)(q + 1024) = t0;
            *(f16x8*)(q + 1032) = z;
            *(f16x8*)(q + 1040) = z;
            *(f16x8*)(q + 1048) = z;
        }
    } else {
        *(f16x8*)(q + lane * 8)       = z;
        *(f16x8*)(q + 512 + lane * 8) = z;
        if (lane < 4) *(f16x8*)(q + 1024 + lane * 8) = z;
    }
}

__global__ void init_keys_kernel(unsigned long long* __restrict__ keys, int M) {
    int b = blockIdx.x * blockDim.x + threadIdx.x;
    if (b < M) keys[b] = ~0ull;
}

// ---- fused MFMA GEMM (acc == d^2 directly) + min/argmin ----
// depth-2 counted-vmcnt pipeline, 3 LDS buffer sets, XCD-chunked swizzle.
__global__ __launch_bounds__(256) void dist_kernel(
        const _Float16* __restrict__ A2, const _Float16* __restrict__ B2,
        unsigned long long* __restrict__ keys, int N, int nXcdChunk)
{
    __shared__ _Float16 lds[3 * 8192];   // 3 sets x (8KB A + 8KB B) = 48KB
    const int tid  = threadIdx.x;
    const int lane = tid & 63;
    const int w    = tid >> 6;
    const int wr   = w >> 1, wc = w & 1;
    const int l15  = lane & 15, lg = lane >> 4;

    // bijective XCD-chunked remap: consecutive blocks on one XCD share the B supertile
    const int bb   = blockIdx.x;
    const int swz  = (bb & 7) * nXcdChunk + (bb >> 3);
    const int mBase = (swz & 15) * BM;
    const long long nSuperBase = (long long)(swz >> 4) * (BN * NSWEEP);

    const int o0 = w * 1024 + lane * 16;   // byte slot in a 4KB stage chunk

    auto STAGE = [&](unsigned bufByte, int tt) {
        const int k0 = (tt % KSTEPS) * BK;
        const long long nB = nSuperBase + (long long)(tt / KSTEPS) * BN;
#pragma unroll
        for (int q = 0; q < 2; ++q) {
            const int o = o0 + q * 4096;
            const int row = o >> 6, cb = o & 63;
            const char* ga = (const char*)A2 + ((size_t)(mBase + row) * K2T + k0) * 2 + cb;
            const char* gb = (const char*)B2 + ((size_t)(nB + row) * K2T + k0) * 2 + cb;
            char* la = (char*)lds + bufByte + q * 4096 + w * 1024;
            __builtin_amdgcn_global_load_lds((glb_t*)ga, (lds_t*)la, 16, 0, 0);
            __builtin_amdgcn_global_load_lds((glb_t*)gb, (lds_t*)(la + 8192), 16, 0, 0);
        }
    };

    unsigned long long key[4][4];
#pragma unroll
    for (int mF = 0; mF < 4; ++mF)
#pragma unroll
        for (int r = 0; r < 4; ++r) key[mF][r] = ~0ull;

    f32x4 acc[4][4];
#pragma unroll
    for (int mF = 0; mF < 4; ++mF)
#pragma unroll
        for (int nF = 0; nF < 4; ++nF) acc[mF][nF] = (f32x4){0.f, 0.f, 0.f, 0.f};

    STAGE(0, 0);
    STAGE(16384, 1);
    unsigned bufR = 0, bufN = 16384, bufP = 32768;

    for (int t = 0; t < TTOT; ++t) {
        // tile t landed (mine); barrier makes it true for all waves. Never drain
        // to 0 mid-loop: tile t+1 stays in flight across the barrier.
        if (t < TTOT - 1) asm volatile("s_waitcnt vmcnt(4)" ::: "memory");
        else              asm volatile("s_waitcnt vmcnt(0)" ::: "memory");
        __builtin_amdgcn_s_barrier();

        const _Float16* As = (const _Float16*)((const char*)lds + bufR);
        const _Float16* Bs = As + 4096;
        f16x8 af[4], bf[4];
#pragma unroll
        for (int mF = 0; mF < 4; ++mF)
            af[mF] = *(const f16x8*)(As + (wr * 64 + mF * 16 + l15) * BK + lg * 8);
#pragma unroll
        for (int nF = 0; nF < 4; ++nF)
            bf[nF] = *(const f16x8*)(Bs + (wc * 64 + nF * 16 + l15) * BK + lg * 8);

        // prefetch tile t+2 into the set freed at the barrier above
        if (t + 2 < TTOT) STAGE(bufP, t + 2);

#pragma unroll
        for (int mF = 0; mF < 4; ++mF)
#pragma unroll
            for (int nF = 0; nF < 4; ++nF)
                acc[mF][nF] = __builtin_amdgcn_mfma_f32_16x16x32_f16(
                    af[mF], bf[nF], acc[mF][nF], 0, 0, 0);

        if (t % KSTEPS == KSTEPS - 1) {       // sweep complete: acc holds d^2
            const long long nBase = nSuperBase + (long long)(t / KSTEPS) * BN;
#pragma unroll
            for (int nF = 0; nF < 4; ++nF) {
                const long long g = nBase + wc * 64 + nF * 16 + l15;
                if (g < N) {
#pragma unroll
                    for (int mF = 0; mF < 4; ++mF)
#pragma unroll
                        for (int r = 0; r < 4; ++r) {
                            float d2 = fmaxf(acc[mF][nF][r], 0.f);
                            unsigned long long kk =
                                ((unsigned long long)__float_as_uint(d2) << 32) |
                                (unsigned long long)(unsigned)g;
                            key[mF][r] = key[mF][r] < kk ? key[mF][r] : kk;
                        }
                }
            }
#pragma unroll
            for (int mF = 0; mF < 4; ++mF)
#pragma unroll
                for (int nF = 0; nF < 4; ++nF) acc[mF][nF] = (f32x4){0.f, 0.f, 0.f, 0.f};
        }

        unsigned tmp = bufR; bufR = bufN; bufN = bufP; bufP = tmp;
    }

    // reduce across the 16 l15-lanes (same output rows, different cols)
#pragma unroll
    for (int mF = 0; mF < 4; ++mF)
#pragma unroll
        for (int r = 0; r < 4; ++r) {
            unsigned long long k = key[mF][r];
#pragma unroll
            for (int m2 = 1; m2 < 16; m2 <<= 1) {
                unsigned long long o = __shfl_xor(k, m2, 16);
                k = k < o ? k : o;
            }
            if (l15 == 0)
                atomicMin(&keys[mBase + wr * 64 + mF * 16 + lg * 4 + r], k);
        }
}

__global__ void finalize_kernel(const unsigned long long* __restrict__ keys,
                                float* __restrict__ out_dist, float* __restrict__ out_idx, int M) {
    int b = blockIdx.x * blockDim.x + threadIdx.x;
    if (b >= M) return;
    unsigned long long k = keys[b];
    float d2 = __uint_as_float((unsigned)(k >> 32));
    out_dist[b] = sqrtf(fmaxf(d2, 0.f));
    out_idx[b]  = (float)(unsigned)(k & 0xffffffffu);  // idx as float VALUE (<2^24 exact)
}

extern "C" void kernel_launch(void* const* d_in, const int* in_sizes, int n_in,
                              void* d_out, int out_size, void* d_ws, size_t ws_size,
                              hipStream_t stream) {
    const float* x  = (const float*)d_in[0];
    const float* db = (const float*)d_in[1];
    float* out = (float*)d_out;

    const int M  = in_sizes[0] / (D * HW);              // 2048
    const int N  = in_sizes[1] / D;                     // 50000
    const int nTiles  = (N + BN - 1) / BN;              // 391
    const int nSupers = (nTiles + NSWEEP - 1) / NSWEEP; // 98
    const int N2 = nSupers * NSWEEP * BN;               // 50176
    const int mTiles = M / BM;                          // 16
    const int nBlocks = nSupers * mTiles;               // 1568 (divisible by 8)
    const int nXcdChunk = nBlocks / 8;                  // 196

    char* ws = (char*)d_ws;
    _Float16* emb2 = (_Float16*)ws;                     // M  x K2T (~4.3 MB)
    _Float16* db2  = emb2 + (size_t)M * K2T;            // N2 x K2T (~106 MB)
    unsigned long long* keys =
        (unsigned long long*)(((uintptr_t)(db2 + (size_t)N2 * K2T) + 7) & ~(uintptr_t)7);

    const int rows = M * D;
    gap_split_kernel<<<(rows + 255) / 256, 256, 0, stream>>>(x, emb2, rows);
    finishA_kernel<<<(M + 3) / 4, 256, 0, stream>>>(emb2, M);
    split_db_kernel<<<(N2 + 3) / 4, 256, 0, stream>>>(db, db2, N, N2);
    init_keys_kernel<<<(M + 255) / 256, 256, 0, stream>>>(keys, M);

    dist_kernel<<<nBlocks, 256, 0, stream>>>(emb2, db2, keys, N, nXcdChunk);

    finalize_kernel<<<(M + 255) / 256, 256, 0, stream>>>(keys, out, out + M, M);
}